// Round 13
// baseline (92.065 us; speedup 1.0000x reference)
//
#include <hip/hip_runtime.h>
#include <math.h>

#define NN 320
#define DFULL 129            // 1 time dim + 128 spatial
#define MIN_DIST_F 0.1f
#define MARGIN_F 0.1f
#define WEIGHT_F 0.1f
#define NTILE 20             // 320/16
#define NTRI (NTILE*(NTILE+1)/2)  // 210 triangular tiles
#define JLEN 80              // j-chunk length
#define NCHUNK 14            // triangle-pruned (kg,jc) chunks per anchor
#define NBLK2 (NN*NCHUNK)    // 4480 loss blocks = 70 groups x 64
#define NGRP 70

// (kg,jc) for chunk y (only chunks whose j-range [80jc,80jc+80) intersects j>64kg):
#define KG_PACK 0x0043322211110000ULL
#define JC_PACK 0x0033232132103210ULL

__device__ __forceinline__ unsigned long long pack2(float a, float b) {
    return (unsigned long long)__float_as_uint(a) |
           ((unsigned long long)__float_as_uint(b) << 32);
}
__device__ __forceinline__ float unpk_lo(unsigned long long u) { return __uint_as_float((unsigned)u); }
__device__ __forceinline__ float unpk_hi(unsigned long long u) { return __uint_as_float((unsigned)(u >> 32)); }

// ---------------- Node 1: Lorentz distances, NaN-poisoned, symmetric (r10 verbatim) ----------------
// Block 0 additionally zeroes the gate region (r7-proven: kernel-boundary ordering
// makes it visible to node 2; NEVER hipMemsetAsync in-graph -- measured ~39us/node).
__device__ __forceinline__ int tri_off(int a) { return a * NTILE - (a * (a - 1)) / 2; }

__global__ __launch_bounds__(256) void lorentz_kernel(const float* __restrict__ E,
                                                      const float* __restrict__ gt,
                                                      float* __restrict__ embp,
                                                      unsigned* __restrict__ gatez) {
    if (blockIdx.x == 0 && threadIdx.x < 160) gatez[threadIdx.x] = 0u;  // garr[70] + gdone
    const int t = blockIdx.x;
    float fa = (2.0f * NTILE + 1.0f - sqrtf((2.0f*NTILE+1.0f)*(2.0f*NTILE+1.0f) - 8.0f * (float)t)) * 0.5f;
    int a = (int)fa;
    if (a > 0 && tri_off(a) > t) --a;
    if (tri_off(a + 1) <= t) ++a;
    const int b = a + (t - tri_off(a));
    const int i0 = a * 16, j0 = b * 16;

    __shared__ float As[16][DFULL];
    __shared__ float Bs[16][DFULL];
    for (int q = threadIdx.x; q < 16 * DFULL; q += 256) {
        int r = q / DFULL, c = q - r * DFULL;
        As[r][c] = E[(i0 + r) * DFULL + c];
        Bs[r][c] = E[(j0 + r) * DFULL + c];
    }
    __syncthreads();
    const int ti = threadIdx.x & 15;
    const int tj = threadIdx.x >> 4;
    const int i = i0 + tj, j = j0 + ti;
    float tt = As[tj][0] * Bs[ti][0];
    float ss = 0.0f;
    #pragma unroll
    for (int d = 1; d < DFULL; ++d) ss = fmaf(As[tj][d], Bs[ti][d], ss);
    float x = fmaxf(tt - ss, 1.0f + 1e-7f);
    float e = acoshf(x);
    float g = gt[i * NN + j];
    float ep = (g >= MIN_DIST_F && i != j) ? e : __builtin_nanf("");
    embp[i * NN + j] = ep;
    embp[j * NN + i] = ep;
}

// ---------------- Node 2: triangle loss (r10 verbatim) + hierarchical tree finalize ----------------
// 4480 one-wave blocks = 70 groups x 64. Per block: one atomicExch(u64 packed partial),
// fence, group-arrival atomicAdd (64-way contention max). 64th arriver: 64 lanes
// atomic-load the group's partials in parallel, fixed-order shuffle reduce, publish
// group sum, bump gdone (70-way). 70th: wave-load 70 group sums -> out. Deterministic
// (all sums are fixed-order trees over exchanged values; no float atomicAdd).
__global__ __launch_bounds__(64) void loss_kernel(const float* __restrict__ embp,
                                                  const float* __restrict__ gt,
                                                  unsigned* __restrict__ garr,      // [70]
                                                  unsigned* __restrict__ gdone,     // [1]
                                                  unsigned long long* __restrict__ gsum,    // [70]
                                                  unsigned long long* __restrict__ partial, // [4480]
                                                  float* __restrict__ out) {
    const int i    = blockIdx.x;                 // anchor
    const int y    = blockIdx.y;                 // chunk id 0..13
    const int kg   = (int)((KG_PACK >> (4 * y)) & 0xF);
    const int jc   = (int)((JC_PACK >> (4 * y)) & 0xF);
    const int lane = threadIdx.x;
    const int k    = (kg << 6) + lane;
    const int bid  = y * NN + i;                 // 0..4479
    const int grp  = bid >> 6;                   // 0..69

    const float* __restrict__ erow = embp + i * NN;
    const float* __restrict__ grow = gt   + i * NN;
    const float ek = erow[k];                    // NaN if k invalid for anchor i
    const float gk = grow[k];
    const int j0 = jc * JLEN;

    float tot = 0.0f;
    int   cnt = 0;
    #pragma unroll
    for (int jb = 0; jb < JLEN; jb += 4) {
        const float4 e4 = *reinterpret_cast<const float4*>(erow + j0 + jb);
        const float4 g4 = *reinterpret_cast<const float4*>(grow + j0 + jb);
        {   const int j = j0 + jb;
            float d = gk - g4.x; float v = fmaf(copysignf(1.0f, d), e4.x - ek, MARGIN_F);
            bool p = (v > 0.0f) && (j > k); tot += p ? v : 0.0f; cnt += (int)__popcll(__ballot(p)); }
        {   const int j = j0 + jb + 1;
            float d = gk - g4.y; float v = fmaf(copysignf(1.0f, d), e4.y - ek, MARGIN_F);
            bool p = (v > 0.0f) && (j > k); tot += p ? v : 0.0f; cnt += (int)__popcll(__ballot(p)); }
        {   const int j = j0 + jb + 2;
            float d = gk - g4.z; float v = fmaf(copysignf(1.0f, d), e4.z - ek, MARGIN_F);
            bool p = (v > 0.0f) && (j > k); tot += p ? v : 0.0f; cnt += (int)__popcll(__ballot(p)); }
        {   const int j = j0 + jb + 3;
            float d = gk - g4.w; float v = fmaf(copysignf(1.0f, d), e4.w - ek, MARGIN_F);
            bool p = (v > 0.0f) && (j > k); tot += p ? v : 0.0f; cnt += (int)__popcll(__ballot(p)); }
    }

    // lane reduce tot (cnt is wave-uniform via ballot)
    for (int off = 32; off > 0; off >>= 1) tot += __shfl_down(tot, off, 64);

    // ---- publish partial + group arrival ----
    unsigned arr = 0u;
    if (lane == 0) {
        atomicExch(&partial[bid], pack2(tot, (float)cnt));
        __threadfence();                         // release
        arr = atomicAdd(&garr[grp], 1u);
    }
    arr = __shfl(arr, 0, 64);
    if (arr != 63u) return;

    // ---- group winner: reduce this group's 64 partials (wave-parallel) ----
    __threadfence();                             // acquire
    unsigned long long p = atomicAdd(&partial[(grp << 6) + lane], 0ull);
    float T = unpk_lo(p), C = unpk_hi(p);
    for (int off = 32; off > 0; off >>= 1) {
        T += __shfl_down(T, off, 64);
        C += __shfl_down(C, off, 64);
    }
    unsigned gd = 0u;
    if (lane == 0) {
        atomicExch(&gsum[grp], pack2(T, C));
        __threadfence();                         // release
        gd = atomicAdd(gdone, 1u);
    }
    gd = __shfl(gd, 0, 64);
    if (gd != (unsigned)(NGRP - 1)) return;

    // ---- global winner: reduce 70 group sums -> out ----
    __threadfence();                             // acquire
    unsigned long long q1 = atomicAdd(&gsum[lane], 0ull);      // lanes 0..63
    float Tt = unpk_lo(q1), Ct = unpk_hi(q1);
    if (lane < NGRP - 64) {                                    // lanes 0..5 take 64..69
        unsigned long long q2 = atomicAdd(&gsum[64 + lane], 0ull);
        Tt += unpk_lo(q2); Ct += unpk_hi(q2);
    }
    for (int off = 32; off > 0; off >>= 1) {
        Tt += __shfl_down(Tt, off, 64);
        Ct += __shfl_down(Ct, off, 64);
    }
    if (lane == 0) out[0] = (Ct > 0.0f) ? WEIGHT_F * Tt / Ct : 0.0f;
}

extern "C" void kernel_launch(void* const* d_in, const int* in_sizes, int n_in,
                              void* d_out, int out_size, void* d_ws, size_t ws_size,
                              hipStream_t stream) {
    const float* E  = (const float*)d_in[0];   // embeddings (320 x 129)
    const float* gt = (const float*)d_in[1];   // tree_distances (320 x 320)
    float* out = (float*)d_out;
    unsigned* gatez = (unsigned*)d_ws;                               // words 0..159 zeroed by node 1
    unsigned* garr  = (unsigned*)d_ws;                               // [70] at +0
    unsigned* gdone = (unsigned*)((char*)d_ws + 512);                // word 128
    unsigned long long* gsum    = (unsigned long long*)((char*)d_ws + 1024);  // [70]
    unsigned long long* partial = (unsigned long long*)((char*)d_ws + 4096);  // [4480]
    float* embp = (float*)((char*)d_ws + 65536);                     // 320*320 f32 = 400 KB

    lorentz_kernel<<<NTRI, 256, 0, stream>>>(E, gt, embp, gatez);
    dim3 g2(NN, NCHUNK);
    loss_kernel<<<g2, 64, 0, stream>>>(embp, gt, garr, gdone, gsum, partial, out);
}

// Round 14
// 18.920 us; speedup vs baseline: 4.8661x; 4.8661x over previous
//
#include <hip/hip_runtime.h>
#include <math.h>

#define NN 320
#define DFULL 129            // 1 time dim + 128 spatial
#define MIN_DIST_F 0.1f
#define MARGIN_F 0.1f
#define WEIGHT_F 0.1f
#define NTILE 20             // 320/16
#define NTRI (NTILE*(NTILE+1)/2)  // 210 triangular tiles
#define NCHUNK 15            // 10 full (jb>kg, compare-free) + 5 diagonal (jb==kg)
#define NPART (NN*NCHUNK)    // 4800 partials

// chunk y -> (kg, jb) of 64: y<10 full pairs (0,1)(0,2)(0,3)(0,4)(1,2)(1,3)(1,4)(2,3)(2,4)(3,4);
// y>=10 diagonal (y-10, y-10). 4-bit nibble packs:
#define KG_PACK 0x432103221110000ULL
#define JB_PACK 0x432104434324321ULL

// ---------------- Kernel 1: Lorentz distances, NaN-poisoned, symmetric (r5 verbatim) ----------------
__device__ __forceinline__ int tri_off(int a) { return a * NTILE - (a * (a - 1)) / 2; }

__global__ __launch_bounds__(256) void lorentz_kernel(const float* __restrict__ E,
                                                      const float* __restrict__ gt,
                                                      float* __restrict__ embp) {
    const int t = blockIdx.x;
    float fa = (2.0f * NTILE + 1.0f - sqrtf((2.0f*NTILE+1.0f)*(2.0f*NTILE+1.0f) - 8.0f * (float)t)) * 0.5f;
    int a = (int)fa;
    if (a > 0 && tri_off(a) > t) --a;
    if (tri_off(a + 1) <= t) ++a;
    const int b = a + (t - tri_off(a));
    const int i0 = a * 16, j0 = b * 16;

    __shared__ float As[16][DFULL];
    __shared__ float Bs[16][DFULL];
    for (int q = threadIdx.x; q < 16 * DFULL; q += 256) {
        int r = q / DFULL, c = q - r * DFULL;
        As[r][c] = E[(i0 + r) * DFULL + c];
        Bs[r][c] = E[(j0 + r) * DFULL + c];
    }
    __syncthreads();
    const int ti = threadIdx.x & 15;
    const int tj = threadIdx.x >> 4;
    const int i = i0 + tj, j = j0 + ti;
    float tt = As[tj][0] * Bs[ti][0];
    float ss = 0.0f;
    #pragma unroll
    for (int d = 1; d < DFULL; ++d) ss = fmaf(As[tj][d], Bs[ti][d], ss);
    float x = fmaxf(tt - ss, 1.0f + 1e-7f);
    float e = acoshf(x);
    float g = gt[i * NN + j];
    float ep = (g >= MIN_DIST_F && i != j) ? e : __builtin_nanf("");
    embp[i * NN + j] = ep;   // symmetric; diagonal tiles double-write same value (benign)
    embp[j * NN + i] = ep;
}

// ---------------- Kernel 2: triangle loss, 64x64 chunks, one wave per (i,chunk) ----------------
// Full chunks (jb>kg): every (j,k) already satisfies j>k -> NO per-term compare.
// Diagonal chunks (jb==kg): per-term j>k (also kills self-pair). Matches triu exactly.
// NaN-poisoned embp kills invalid pairs: v NaN -> (v>0) false -> cndmask adds 0
// (never multiply-by-flag: 0*NaN=NaN). cnt = float cndmask adds (r5-proven; NO ballot
// -- r10's per-term ballot was the suspected 1.7us regression: vcc->SGPR per term).
__global__ __launch_bounds__(64) void loss_kernel(const float* __restrict__ embp,
                                                  const float* __restrict__ gt,
                                                  float2* __restrict__ partial) {
    const int i    = blockIdx.x;                 // anchor
    const int y    = blockIdx.y;                 // chunk id 0..14
    const int kg   = (int)((KG_PACK >> (4 * y)) & 0xF);
    const int jb   = (int)((JB_PACK >> (4 * y)) & 0xF);
    const int lane = threadIdx.x;
    const int k    = (kg << 6) + lane;

    const float* __restrict__ erow = embp + i * NN;
    const float* __restrict__ grow = gt   + i * NN;
    const float ek = erow[k];                    // NaN if k invalid for anchor i
    const float gk = grow[k];
    const int j0 = jb << 6;

    float tot = 0.0f, cnt = 0.0f;
    if (y < 10) {
        // full chunk: j in [j0, j0+64), all j > k guaranteed
        #pragma unroll
        for (int jq = 0; jq < 64; jq += 4) {
            const float4 e4 = *reinterpret_cast<const float4*>(erow + j0 + jq);
            const float4 g4 = *reinterpret_cast<const float4*>(grow + j0 + jq);
            {   float d = gk - g4.x; float v = fmaf(copysignf(1.0f, d), e4.x - ek, MARGIN_F);
                bool p = v > 0.0f; tot += p ? v : 0.0f; cnt += p ? 1.0f : 0.0f; }
            {   float d = gk - g4.y; float v = fmaf(copysignf(1.0f, d), e4.y - ek, MARGIN_F);
                bool p = v > 0.0f; tot += p ? v : 0.0f; cnt += p ? 1.0f : 0.0f; }
            {   float d = gk - g4.z; float v = fmaf(copysignf(1.0f, d), e4.z - ek, MARGIN_F);
                bool p = v > 0.0f; tot += p ? v : 0.0f; cnt += p ? 1.0f : 0.0f; }
            {   float d = gk - g4.w; float v = fmaf(copysignf(1.0f, d), e4.w - ek, MARGIN_F);
                bool p = v > 0.0f; tot += p ? v : 0.0f; cnt += p ? 1.0f : 0.0f; }
        }
    } else {
        // diagonal chunk: j in [j0, j0+64) with j > k (k in same 64-range)
        #pragma unroll
        for (int jq = 0; jq < 64; jq += 4) {
            const float4 e4 = *reinterpret_cast<const float4*>(erow + j0 + jq);
            const float4 g4 = *reinterpret_cast<const float4*>(grow + j0 + jq);
            {   const int j = j0 + jq;
                float d = gk - g4.x; float v = fmaf(copysignf(1.0f, d), e4.x - ek, MARGIN_F);
                bool p = (v > 0.0f) && (j > k); tot += p ? v : 0.0f; cnt += p ? 1.0f : 0.0f; }
            {   const int j = j0 + jq + 1;
                float d = gk - g4.y; float v = fmaf(copysignf(1.0f, d), e4.y - ek, MARGIN_F);
                bool p = (v > 0.0f) && (j > k); tot += p ? v : 0.0f; cnt += p ? 1.0f : 0.0f; }
            {   const int j = j0 + jq + 2;
                float d = gk - g4.z; float v = fmaf(copysignf(1.0f, d), e4.z - ek, MARGIN_F);
                bool p = (v > 0.0f) && (j > k); tot += p ? v : 0.0f; cnt += p ? 1.0f : 0.0f; }
            {   const int j = j0 + jq + 3;
                float d = gk - g4.w; float v = fmaf(copysignf(1.0f, d), e4.w - ek, MARGIN_F);
                bool p = (v > 0.0f) && (j > k); tot += p ? v : 0.0f; cnt += p ? 1.0f : 0.0f; }
        }
    }

    // wave64 reduce
    for (int off = 32; off > 0; off >>= 1) {
        tot += __shfl_down(tot, off, 64);
        cnt += __shfl_down(cnt, off, 64);
    }
    if (lane == 0) partial[y * NN + i] = make_float2(tot, cnt);
}

// ---------------- Kernel 3: reduce 4800 partials, finalize ----------------
__global__ __launch_bounds__(NN) void finalize_kernel(const float2* __restrict__ partial,
                                                      float* __restrict__ out) {
    const int t = threadIdx.x;
    float T = 0.0f, C = 0.0f;
    #pragma unroll
    for (int q = 0; q < NCHUNK; ++q) {           // 15 coalesced float2 reads
        float2 p = partial[q * NN + t];
        T += p.x; C += p.y;
    }
    for (int off = 32; off > 0; off >>= 1) {
        T += __shfl_down(T, off, 64);
        C += __shfl_down(C, off, 64);
    }
    __shared__ float wt[5], wc[5];
    const int lane = t & 63, wid = t >> 6;
    if (lane == 0) { wt[wid] = T; wc[wid] = C; }
    __syncthreads();
    if (t == 0) {
        float Tt = 0.0f, Ct = 0.0f;
        #pragma unroll
        for (int w = 0; w < 5; w++) { Tt += wt[w]; Ct += wc[w]; }
        out[0] = (Ct > 0.0f) ? WEIGHT_F * Tt / Ct : 0.0f;
    }
}

extern "C" void kernel_launch(void* const* d_in, const int* in_sizes, int n_in,
                              void* d_out, int out_size, void* d_ws, size_t ws_size,
                              hipStream_t stream) {
    const float* E  = (const float*)d_in[0];   // embeddings (320 x 129)
    const float* gt = (const float*)d_in[1];   // tree_distances (320 x 320)
    float* out = (float*)d_out;
    float2* partial = (float2*)d_ws;                      // 4800 float2 = 38.4 KB
    float*  embp = (float*)((char*)d_ws + 65536);         // 320*320 f32 = 400 KB

    lorentz_kernel<<<NTRI, 256, 0, stream>>>(E, gt, embp);
    dim3 g2(NN, NCHUNK);
    loss_kernel<<<g2, 64, 0, stream>>>(embp, gt, partial);
    finalize_kernel<<<1, NN, 0, stream>>>(partial, out);
}

// Round 15
// 18.612 us; speedup vs baseline: 4.9465x; 1.0165x over previous
//
#include <hip/hip_runtime.h>
#include <math.h>

#define NN 320
#define DFULL 129            // 1 time dim + 128 spatial
#define MIN_DIST_F 0.1f
#define MARGIN_F 0.1f
#define WEIGHT_F 0.1f
#define NTILE 20             // 320/16
#define NTRI (NTILE*(NTILE+1)/2)  // 210 triangular tiles
#define NCHUNK 15            // 10 full (jb>kg, compare-free) + 5 diagonal (jb==kg)
#define NPART (NN*NCHUNK)    // 4800 partials = 75 * 64

// chunk y -> (kg, jb) of 64: y<10 full pairs (0,1)(0,2)(0,3)(0,4)(1,2)(1,3)(1,4)(2,3)(2,4)(3,4);
// y>=10 diagonal (y-10, y-10). 4-bit nibble packs:
#define KG_PACK 0x432103221110000ULL
#define JB_PACK 0x432104434324321ULL

// ---------------- Kernel 1: Lorentz distances, NaN-poisoned, symmetric ----------------
// r13 verbatim except: dot accumulated in TWO independent chains (even/odd d) --
// at 210 blocks (<1/CU, ~1 wave/SIMD) the single 129-FMA dependent chain (~516cy)
// was latency-exposed; dual chains halve it.
__device__ __forceinline__ int tri_off(int a) { return a * NTILE - (a * (a - 1)) / 2; }

__global__ __launch_bounds__(256) void lorentz_kernel(const float* __restrict__ E,
                                                      const float* __restrict__ gt,
                                                      float* __restrict__ embp) {
    const int t = blockIdx.x;
    float fa = (2.0f * NTILE + 1.0f - sqrtf((2.0f*NTILE+1.0f)*(2.0f*NTILE+1.0f) - 8.0f * (float)t)) * 0.5f;
    int a = (int)fa;
    if (a > 0 && tri_off(a) > t) --a;
    if (tri_off(a + 1) <= t) ++a;
    const int b = a + (t - tri_off(a));
    const int i0 = a * 16, j0 = b * 16;

    __shared__ float As[16][DFULL];
    __shared__ float Bs[16][DFULL];
    for (int q = threadIdx.x; q < 16 * DFULL; q += 256) {
        int r = q / DFULL, c = q - r * DFULL;
        As[r][c] = E[(i0 + r) * DFULL + c];
        Bs[r][c] = E[(j0 + r) * DFULL + c];
    }
    __syncthreads();
    const int ti = threadIdx.x & 15;
    const int tj = threadIdx.x >> 4;
    const int i = i0 + tj, j = j0 + ti;
    float tt = As[tj][0] * Bs[ti][0];
    float ss0 = 0.0f, ss1 = 0.0f;          // two independent FMA chains
    #pragma unroll
    for (int d = 1; d < DFULL; d += 2) {
        ss0 = fmaf(As[tj][d],     Bs[ti][d],     ss0);
        ss1 = fmaf(As[tj][d + 1], Bs[ti][d + 1], ss1);
    }
    float x = fmaxf(tt - (ss0 + ss1), 1.0f + 1e-7f);
    float e = acoshf(x);
    float g = gt[i * NN + j];
    float ep = (g >= MIN_DIST_F && i != j) ? e : __builtin_nanf("");
    embp[i * NN + j] = ep;   // symmetric; diagonal tiles double-write same value (benign)
    embp[j * NN + i] = ep;
}

// ---------------- Kernel 2: triangle loss, 64x64 chunks (r13 VERBATIM -- proven 18.9) ----------------
__global__ __launch_bounds__(64) void loss_kernel(const float* __restrict__ embp,
                                                  const float* __restrict__ gt,
                                                  float2* __restrict__ partial) {
    const int i    = blockIdx.x;                 // anchor
    const int y    = blockIdx.y;                 // chunk id 0..14
    const int kg   = (int)((KG_PACK >> (4 * y)) & 0xF);
    const int jb   = (int)((JB_PACK >> (4 * y)) & 0xF);
    const int lane = threadIdx.x;
    const int k    = (kg << 6) + lane;

    const float* __restrict__ erow = embp + i * NN;
    const float* __restrict__ grow = gt   + i * NN;
    const float ek = erow[k];                    // NaN if k invalid for anchor i
    const float gk = grow[k];
    const int j0 = jb << 6;

    float tot = 0.0f, cnt = 0.0f;
    if (y < 10) {
        // full chunk: j in [j0, j0+64), all j > k guaranteed -> compare-free
        #pragma unroll
        for (int jq = 0; jq < 64; jq += 4) {
            const float4 e4 = *reinterpret_cast<const float4*>(erow + j0 + jq);
            const float4 g4 = *reinterpret_cast<const float4*>(grow + j0 + jq);
            {   float d = gk - g4.x; float v = fmaf(copysignf(1.0f, d), e4.x - ek, MARGIN_F);
                bool p = v > 0.0f; tot += p ? v : 0.0f; cnt += p ? 1.0f : 0.0f; }
            {   float d = gk - g4.y; float v = fmaf(copysignf(1.0f, d), e4.y - ek, MARGIN_F);
                bool p = v > 0.0f; tot += p ? v : 0.0f; cnt += p ? 1.0f : 0.0f; }
            {   float d = gk - g4.z; float v = fmaf(copysignf(1.0f, d), e4.z - ek, MARGIN_F);
                bool p = v > 0.0f; tot += p ? v : 0.0f; cnt += p ? 1.0f : 0.0f; }
            {   float d = gk - g4.w; float v = fmaf(copysignf(1.0f, d), e4.w - ek, MARGIN_F);
                bool p = v > 0.0f; tot += p ? v : 0.0f; cnt += p ? 1.0f : 0.0f; }
        }
    } else {
        // diagonal chunk: j in [j0, j0+64) with j > k (also kills self-pair)
        #pragma unroll
        for (int jq = 0; jq < 64; jq += 4) {
            const float4 e4 = *reinterpret_cast<const float4*>(erow + j0 + jq);
            const float4 g4 = *reinterpret_cast<const float4*>(grow + j0 + jq);
            {   const int j = j0 + jq;
                float d = gk - g4.x; float v = fmaf(copysignf(1.0f, d), e4.x - ek, MARGIN_F);
                bool p = (v > 0.0f) && (j > k); tot += p ? v : 0.0f; cnt += p ? 1.0f : 0.0f; }
            {   const int j = j0 + jq + 1;
                float d = gk - g4.y; float v = fmaf(copysignf(1.0f, d), e4.y - ek, MARGIN_F);
                bool p = (v > 0.0f) && (j > k); tot += p ? v : 0.0f; cnt += p ? 1.0f : 0.0f; }
            {   const int j = j0 + jq + 2;
                float d = gk - g4.z; float v = fmaf(copysignf(1.0f, d), e4.z - ek, MARGIN_F);
                bool p = (v > 0.0f) && (j > k); tot += p ? v : 0.0f; cnt += p ? 1.0f : 0.0f; }
            {   const int j = j0 + jq + 3;
                float d = gk - g4.w; float v = fmaf(copysignf(1.0f, d), e4.w - ek, MARGIN_F);
                bool p = (v > 0.0f) && (j > k); tot += p ? v : 0.0f; cnt += p ? 1.0f : 0.0f; }
        }
    }

    // wave64 reduce
    for (int off = 32; off > 0; off >>= 1) {
        tot += __shfl_down(tot, off, 64);
        cnt += __shfl_down(cnt, off, 64);
    }
    if (lane == 0) partial[y * NN + i] = make_float2(tot, cnt);
}

// ---------------- Kernel 3: single-wave finalize (no LDS, no sync) ----------------
__global__ __launch_bounds__(64) void finalize_kernel(const float2* __restrict__ partial,
                                                      float* __restrict__ out) {
    const int lane = threadIdx.x;
    float T = 0.0f, C = 0.0f;
    #pragma unroll
    for (int q = 0; q < NPART / 64; ++q) {       // 75 coalesced float2 reads/lane
        float2 p = partial[q * 64 + lane];
        T += p.x; C += p.y;
    }
    for (int off = 32; off > 0; off >>= 1) {
        T += __shfl_down(T, off, 64);
        C += __shfl_down(C, off, 64);
    }
    if (lane == 0) out[0] = (C > 0.0f) ? WEIGHT_F * T / C : 0.0f;
}

extern "C" void kernel_launch(void* const* d_in, const int* in_sizes, int n_in,
                              void* d_out, int out_size, void* d_ws, size_t ws_size,
                              hipStream_t stream) {
    const float* E  = (const float*)d_in[0];   // embeddings (320 x 129)
    const float* gt = (const float*)d_in[1];   // tree_distances (320 x 320)
    float* out = (float*)d_out;
    float2* partial = (float2*)d_ws;                      // 4800 float2 = 38.4 KB
    float*  embp = (float*)((char*)d_ws + 65536);         // 320*320 f32 = 400 KB

    lorentz_kernel<<<NTRI, 256, 0, stream>>>(E, gt, embp);
    dim3 g2(NN, NCHUNK);
    loss_kernel<<<g2, 64, 0, stream>>>(embp, gt, partial);
    finalize_kernel<<<1, 64, 0, stream>>>(partial, out);
}